// Round 1
// baseline (674.714 us; speedup 1.0000x reference)
//
#include <hip/hip_runtime.h>

typedef _Float16 f16;
typedef _Float16 f16x8 __attribute__((ext_vector_type(8)));
typedef float f32x4 __attribute__((ext_vector_type(4)));

#define NB 8
#define NC 128          // cin = cout
#define HW 256
#define EPSV 1e-8f

// ---------------------------------------------------------------------------
// Kernel 1: gamma = y @ gamma_w^T + gamma_b; w = conv_w*(gamma+1); demod;
// write f16 W in layout [b][tap(9)][chunk(4)][co(128)][ci_in(32)]
// ---------------------------------------------------------------------------
__global__ __launch_bounds__(256) void k_weights(
    const float* __restrict__ y, const float* __restrict__ conv_w,
    const float* __restrict__ gamma_w, const float* __restrict__ gamma_b,
    f16* __restrict__ W16)
{
    int b  = blockIdx.x >> 7;
    int co = blockIdx.x & 127;
    int t  = threadIdx.x;

    __shared__ float g1[128];
    __shared__ float part[256];
    __shared__ float red[256];

    // gamma: each of 256 threads sums half a row
    {
        int ci = t & 127, hf = t >> 7;
        const float* yb = y + b * 128 + hf * 64;
        const float* gw = gamma_w + (size_t)ci * 128 + hf * 64;
        float s = 0.f;
        #pragma unroll 8
        for (int j = 0; j < 64; ++j) s += yb[j] * gw[j];
        part[t] = s;
    }
    __syncthreads();
    if (t < 128) g1[t] = part[t] + part[t + 128] + gamma_b[t] + 1.0f;
    __syncthreads();

    const float* wrow = conv_w + (size_t)co * 1152;
    float ssq = 0.f;
    for (int i = t; i < 1152; i += 256) {
        int ci = i / 9;
        float wv = wrow[i] * g1[ci];
        ssq += wv * wv;
    }
    red[t] = ssq;
    __syncthreads();
    for (int s = 128; s > 0; s >>= 1) {
        if (t < s) red[t] += red[t + s];
        __syncthreads();
    }
    float d = rsqrtf(red[0] + EPSV);

    for (int i = t; i < 1152; i += 256) {
        int ci = i / 9, tap = i - ci * 9;
        float wv = wrow[i] * g1[ci] * d;
        int chunk = ci >> 5, ci_in = ci & 31;
        size_t wi = (((size_t)((b * 9 + tap) * 4 + chunk) * 128 + co) << 5) + ci_in;
        W16[wi] = (f16)wv;
    }
}

// ---------------------------------------------------------------------------
// Kernel 2: x NCHW fp32 -> f16 layout [b][chunk(4)][y][x][ci_in(32)]
// block = (b, y); 256 threads = 256 x-columns; loop over 128 channels
// ---------------------------------------------------------------------------
__global__ __launch_bounds__(256) void k_transpose(
    const float* __restrict__ x, f16* __restrict__ x16)
{
    int b = blockIdx.x >> 8;
    int y = blockIdx.x & 255;
    int l = threadIdx.x;

    const float* src = x + ((size_t)b * 128 * 65536) + (size_t)y * 256 + l;

    for (int c0 = 0; c0 < 128; c0 += 8) {
        uint u[4];
        #pragma unroll
        for (int i = 0; i < 8; i += 2) {
            float v0 = src[(size_t)(c0 + i) * 65536];
            float v1 = src[(size_t)(c0 + i + 1) * 65536];
            f16 h0 = (f16)v0, h1 = (f16)v1;
            ushort u0 = *(ushort*)&h0, u1 = *(ushort*)&h1;
            u[i >> 1] = (uint)u0 | ((uint)u1 << 16);
        }
        int chunk = c0 >> 5, ci_in = c0 & 31;
        f16* dst = x16 + (((size_t)(b * 4 + chunk) * 65536 + (size_t)y * 256 + l) << 5) + ci_in;
        *(uint4*)dst = *(uint4*)u;
    }
}

// ---------------------------------------------------------------------------
// Kernel 3: implicit-GEMM grouped conv. Block: 128 cout x (8 rows x 16 cols).
// K-loop: chunk(4) x tap(9); mfma_f32_16x16x32_f16; 4 waves 2x2, 64x64/wave.
// ---------------------------------------------------------------------------
__device__ __forceinline__ uint4 load_xs_g(const f16* xc, int idx, int y0, int x0)
{
    int r = idx / 72;                 // 72 granules (16B) per halo row
    int rem = idx - r * 72;
    int yy = y0 + r - 1;
    int xx = x0 + (rem >> 2) - 1;
    if ((unsigned)yy < 256u && (unsigned)xx < 256u)
        return *(const uint4*)(xc + ((((size_t)yy << 8) + xx) << 5) + ((rem & 3) << 3));
    return make_uint4(0u, 0u, 0u, 0u);
}

__global__ __launch_bounds__(256) void k_conv(
    const f16* __restrict__ x16, const f16* __restrict__ W16,
    float* __restrict__ out)
{
    int blk  = blockIdx.x;
    int tile = blk & 511;
    int b    = blk >> 9;
    int tc   = tile & 15, tr = tile >> 4;
    int y0   = tr * 8, x0 = tc * 16;

    __shared__ f16 As[2][128 * 40];   // A tile, pitch 40 f16 (80B) per co
    __shared__ f16 Xs[2][180 * 32];   // 10x18 halo pixels x 32 ci

    int t    = threadIdx.x;
    int w    = t >> 6, lane = t & 63;
    int wm   = (w >> 1) * 64;         // cout base for this wave
    int wn   = (w & 1) * 4;           // output-row base for this wave
    int l15  = lane & 15;
    int k8   = lane >> 4;

    const f16* Wb = W16 + (size_t)b * 147456;   // 9*4*128*32

    // prologue: stage xs chunk0 -> buf0, A (tap0,chunk0) -> buf0
    {
        const f16* xc = x16 + (size_t)(b * 4) * 2097152;
        for (int idx = t; idx < 720; idx += 256) {
            uint4 v = load_xs_g(xc, idx, y0, x0);
            *(uint4*)((char*)(&Xs[0][0]) + (size_t)idx * 16) = v;
        }
        const uint4* asrc = (const uint4*)Wb;
        uint4* adst = (uint4*)((char*)(&As[0][0]) + (t >> 1) * 80 + (t & 1) * 32);
        adst[0] = asrc[(t >> 1) * 4 + (t & 1) * 2];
        adst[1] = asrc[(t >> 1) * 4 + (t & 1) * 2 + 1];
    }
    __syncthreads();

    f32x4 acc[4][4];
    #pragma unroll
    for (int mi = 0; mi < 4; ++mi)
        #pragma unroll
        for (int nj = 0; nj < 4; ++nj)
            acc[mi][nj] = (f32x4){0.f, 0.f, 0.f, 0.f};

    int chunk = 0, tap = 0;
    for (int it = 0; it < 36; ++it) {
        bool preA = it < 35;
        bool preX = (tap == 0) && (chunk < 3);

        // issue prefetch global loads early
        uint4 a0 = {}, a1 = {};
        if (preA) {
            int tn = tap + 1, cn = chunk;
            if (tn == 9) { tn = 0; cn = chunk + 1; }
            const uint4* asrc = (const uint4*)(Wb + (size_t)(tn * 4 + cn) * 4096);
            a0 = asrc[(t >> 1) * 4 + (t & 1) * 2];
            a1 = asrc[(t >> 1) * 4 + (t & 1) * 2 + 1];
        }
        uint4 xv0 = {}, xv1 = {}, xv2 = {};
        if (preX) {
            const f16* xc = x16 + (size_t)(b * 4 + chunk + 1) * 2097152;
            xv0 = load_xs_g(xc, t, y0, x0);
            xv1 = load_xs_g(xc, t + 256, y0, x0);
            if (t < 208) xv2 = load_xs_g(xc, t + 512, y0, x0);
        }

        // fragments
        int dy = tap / 3, dx = tap - dy * 3;
        const f16* Ab = &As[it & 1][0];
        const f16* Xb = &Xs[chunk & 1][0];

        f16x8 af[4];
        #pragma unroll
        for (int mi = 0; mi < 4; ++mi)
            af[mi] = *(const f16x8*)(Ab + (wm + mi * 16 + l15) * 40 + k8 * 8);

        f16x8 bf[4];
        #pragma unroll
        for (int nj = 0; nj < 4; ++nj) {
            int p = (wn + nj + dy) * 18 + dx + l15;
            bf[nj] = *(const f16x8*)(Xb + p * 32 + k8 * 8);
        }

        #pragma unroll
        for (int mi = 0; mi < 4; ++mi)
            #pragma unroll
            for (int nj = 0; nj < 4; ++nj)
                acc[mi][nj] = __builtin_amdgcn_mfma_f32_16x16x32_f16(
                    af[mi], bf[nj], acc[mi][nj], 0, 0, 0);

        // drain prefetches into the other buffers
        if (preA) {
            uint4* adst = (uint4*)((char*)(&As[(it + 1) & 1][0]) + (t >> 1) * 80 + (t & 1) * 32);
            adst[0] = a0; adst[1] = a1;
        }
        if (preX) {
            char* xd = (char*)(&Xs[(chunk + 1) & 1][0]);
            *(uint4*)(xd + (size_t)t * 16) = xv0;
            *(uint4*)(xd + (size_t)(t + 256) * 16) = xv1;
            if (t < 208) *(uint4*)(xd + (size_t)(t + 512) * 16) = xv2;
        }
        __syncthreads();

        if (++tap == 9) { tap = 0; ++chunk; }
    }

    // epilogue: C/D layout col = lane&15 (pixel col), row = (lane>>4)*4 + reg (cout)
    size_t obase = (size_t)b << 23;   // b*128*65536
    #pragma unroll
    for (int mi = 0; mi < 4; ++mi) {
        #pragma unroll
        for (int r = 0; r < 4; ++r) {
            int co = wm + mi * 16 + k8 * 4 + r;
            float* orow = out + obase + ((size_t)co << 16);
            #pragma unroll
            for (int nj = 0; nj < 4; ++nj) {
                int yy = y0 + wn + nj;
                orow[(size_t)yy * 256 + x0 + l15] = acc[mi][nj][r];
            }
        }
    }
}

// ---------------------------------------------------------------------------
extern "C" void kernel_launch(void* const* d_in, const int* in_sizes, int n_in,
                              void* d_out, int out_size, void* d_ws, size_t ws_size,
                              hipStream_t stream)
{
    const float* x       = (const float*)d_in[0];
    const float* y       = (const float*)d_in[1];
    const float* conv_w  = (const float*)d_in[2];
    const float* gamma_w = (const float*)d_in[3];
    const float* gamma_b = (const float*)d_in[4];
    float* out = (float*)d_out;

    f16* x16 = (f16*)d_ws;                                    // 134,217,728 B
    f16* W16 = (f16*)((char*)d_ws + 134217728ull);            // 2,359,296 B

    k_weights<<<dim3(1024), dim3(256), 0, stream>>>(y, conv_w, gamma_w, gamma_b, W16);
    k_transpose<<<dim3(2048), dim3(256), 0, stream>>>(x, x16);
    k_conv<<<dim3(4096), dim3(256), 0, stream>>>(x16, W16, out);
}